// Round 8
// baseline (307.524 us; speedup 1.0000x reference)
//
#include <hip/hip_runtime.h>
#include <hip/hip_fp16.h>
#include <math.h>

#define N_NODES 50000
#define E_EDGES 800000
#define NEG_SLOPE 0.2f
#define BN_EPS 1e-5f

#define BK_SHIFT 9                       // 512-node buckets
#define NBK 98                           // ceil(50000/512)
#define L1_BLOCKS 256
#define L1_CHUNK (E_EDGES / L1_BLOCKS)   // 3125 exactly
#define CNT_N (NBK * L1_BLOCKS)          // 25088
#define SCG_BLOCKS ((CNT_N + 1023) / 1024)  // 25
#define STAGE_MAX 9216                   // per-bucket staging

typedef __attribute__((ext_vector_type(8))) _Float16 half8;
typedef __attribute__((ext_vector_type(4))) float f32x4;

__device__ __forceinline__ float lrelu(float v) { return v > 0.f ? v : NEG_SLOPE * v; }

// ---------------- init (BN accumulators only) ----------------
__global__ void k_zero(float* __restrict__ bn_sum, float* __restrict__ bn_sumsq) {
  int t = threadIdx.x;
  if (t < 128) { bn_sum[t] = 0.f; bn_sumsq[t] = 0.f; }
}

// ---------------- fp16 converts ----------------
__global__ __launch_bounds__(256) void k_cvtx(const float* __restrict__ x,
                                              _Float16* __restrict__ xh) {
  int i = blockIdx.x * 256 + threadIdx.x;  // 8 floats each; grid*256*8 == 6.4M exactly
  const float4* p = (const float4*)x + (size_t)i * 2;
  float4 a = p[0], b = p[1];
  half8 o = {(_Float16)a.x, (_Float16)a.y, (_Float16)a.z, (_Float16)a.w,
             (_Float16)b.x, (_Float16)b.y, (_Float16)b.z, (_Float16)b.w};
  *((half8*)xh + i) = o;
}

__global__ void k_cvtW(const float* __restrict__ W0, const float* __restrict__ W1,
                       _Float16* __restrict__ W0t, _Float16* __restrict__ W1t) {
  int t = threadIdx.x;
  for (int idx = t; idx < 128 * 128; idx += 256) {
    int k = idx >> 7, c = idx & 127;
    W0t[c * 128 + k] = (_Float16)W0[idx];
  }
  for (int idx = t; idx < 128 * 64; idx += 256) {
    int k = idx >> 6, c = idx & 63;
    W1t[c * 128 + k] = (_Float16)W1[idx];
  }
}

// BN+ELU fused fp32->fp16 convert of out0
__global__ __launch_bounds__(256) void k_cvty(const float* __restrict__ x,
                                              const float* __restrict__ scale,
                                              const float* __restrict__ shift,
                                              _Float16* __restrict__ yh) {
  int i = blockIdx.x * 256 + threadIdx.x;  // 8 floats each
  int c = (i * 8) & 127;
  float4 s0 = *(const float4*)&scale[c], s1 = *(const float4*)&scale[c + 4];
  float4 f0 = *(const float4*)&shift[c], f1 = *(const float4*)&shift[c + 4];
  const float4* p = (const float4*)x + (size_t)i * 2;
  float4 a = p[0], b = p[1];
  float v[8];
  v[0] = a.x * s0.x + f0.x; v[1] = a.y * s0.y + f0.y;
  v[2] = a.z * s0.z + f0.z; v[3] = a.w * s0.w + f0.w;
  v[4] = b.x * s1.x + f1.x; v[5] = b.y * s1.y + f1.y;
  v[6] = b.z * s1.z + f1.z; v[7] = b.w * s1.w + f1.w;
  half8 o;
#pragma unroll
  for (int j = 0; j < 8; j++) {
    float e = v[j] > 0.f ? v[j] : __expf(v[j]) - 1.f;
    o[j] = (_Float16)e;
  }
  *((half8*)yh + i) = o;
}

// ---- L1: per-block bucket histogram ----
__global__ __launch_bounds__(256) void k_l1hist(const int* __restrict__ dst,
                                                int* __restrict__ cnt) {
  __shared__ int lcnt[NBK];
  int t = threadIdx.x;
  if (t < NBK) lcnt[t] = 0;
  __syncthreads();
  int beg = blockIdx.x * L1_CHUNK, end = beg + L1_CHUNK;
  for (int e = beg + t; e < end; e += 256)
    atomicAdd(&lcnt[((unsigned int)dst[e]) >> BK_SHIFT], 1);
  __syncthreads();
  for (int b = t; b < NBK; b += 256) cnt[b * L1_BLOCKS + blockIdx.x] = lcnt[b];
}

// ---- hierarchical exclusive scan over CNT_N ----
__global__ __launch_bounds__(256) void k_scan1g(const int* __restrict__ cnt,
                                                int* __restrict__ tmp,
                                                int* __restrict__ bsums) {
  __shared__ int ts[256];
  int t = threadIdx.x;
  int base = blockIdx.x * 1024 + t * 4;
  int c0 = (base + 0 < CNT_N) ? cnt[base + 0] : 0;
  int c1 = (base + 1 < CNT_N) ? cnt[base + 1] : 0;
  int c2 = (base + 2 < CNT_N) ? cnt[base + 2] : 0;
  int c3 = (base + 3 < CNT_N) ? cnt[base + 3] : 0;
  int s = c0 + c1 + c2 + c3;
  ts[t] = s;
  __syncthreads();
  for (int off = 1; off < 256; off <<= 1) {
    int v = (t >= off) ? ts[t - off] : 0;
    __syncthreads();
    ts[t] += v;
    __syncthreads();
  }
  int excl = ts[t] - s;
  if (t == 255) bsums[blockIdx.x] = ts[255];
  if (base + 0 < CNT_N) tmp[base + 0] = excl;
  if (base + 1 < CNT_N) tmp[base + 1] = excl + c0;
  if (base + 2 < CNT_N) tmp[base + 2] = excl + c0 + c1;
  if (base + 3 < CNT_N) tmp[base + 3] = excl + c0 + c1 + c2;
}

__global__ void k_scan2g(int* __restrict__ bsums) {
  int t = threadIdx.x;
  int orig = (t < SCG_BLOCKS) ? bsums[t] : 0;
  int v = orig;
#pragma unroll
  for (int off = 1; off < 64; off <<= 1) {
    int u = __shfl_up(v, off);
    if (t >= off) v += u;
  }
  if (t < SCG_BLOCKS) bsums[t] = v - orig;
}

// ---- L1 scatter: deterministic bases per (bucket,block) ----
__global__ __launch_bounds__(256) void k_l1scatter(const int* __restrict__ src,
                                                   const int* __restrict__ dst,
                                                   const int* __restrict__ tmp,
                                                   const int* __restrict__ bsums,
                                                   unsigned int* __restrict__ binned) {
  __shared__ int cur[NBK];
  int t = threadIdx.x;
  for (int b = t; b < NBK; b += 256) {
    int idx = b * L1_BLOCKS + blockIdx.x;
    cur[b] = tmp[idx] + bsums[idx >> 10];
  }
  __syncthreads();
  int beg = blockIdx.x * L1_CHUNK, end = beg + L1_CHUNK;
  for (int e = beg + t; e < end; e += 256) {
    unsigned int d = (unsigned int)dst[e];
    int b = d >> BK_SHIFT;
    int p = atomicAdd(&cur[b], 1);
    binned[p] = ((unsigned int)src[e] << 16) | d;
  }
}

__global__ void k_bbase(const int* __restrict__ tmp, const int* __restrict__ bsums,
                        int* __restrict__ bucket_base) {
  int b = threadIdx.x;
  if (b < NBK) {
    int idx = b * L1_BLOCKS;
    bucket_base[b] = tmp[idx] + bsums[idx >> 10];
  }
  if (b == NBK) bucket_base[NBK] = E_EDGES;
}

// ---- L2: per-bucket LDS counting sort ----
__global__ __launch_bounds__(256) void k_scatter3(const int* __restrict__ bucket_base,
                                                  const unsigned int* __restrict__ binned,
                                                  int* __restrict__ row_ptr,
                                                  int* __restrict__ csr_src) {
  __shared__ int cnt[512];
  __shared__ int staging[STAGE_MAX];
  __shared__ int ts[256];
  int t = threadIdx.x;
  int b = blockIdx.x;
  int lo = b << BK_SHIFT;
  int hi = lo + 512; if (hi > N_NODES) hi = N_NODES;
  int nloc = hi - lo;
  int base = bucket_base[b];
  int end = bucket_base[b + 1];
  cnt[t] = 0; cnt[t + 256] = 0;
  __syncthreads();
  for (int i = base + t; i < end; i += 256)
    atomicAdd(&cnt[(binned[i] & 0xFFFFu) - lo], 1);
  __syncthreads();
  int c0 = cnt[2 * t], c1 = cnt[2 * t + 1];
  int pair = c0 + c1;
  ts[t] = pair;
  __syncthreads();
  for (int off = 1; off < 256; off <<= 1) {
    int v = (t >= off) ? ts[t - off] : 0;
    __syncthreads();
    ts[t] += v;
    __syncthreads();
  }
  int exclp = ts[t] - pair;
  cnt[2 * t] = exclp;
  cnt[2 * t + 1] = exclp + c0;
  if (2 * t < nloc) row_ptr[lo + 2 * t] = base + exclp;
  if (2 * t + 1 < nloc) row_ptr[lo + 2 * t + 1] = base + exclp + c0;
  if (b == NBK - 1 && t == 0) row_ptr[N_NODES] = E_EDGES;
  __syncthreads();
  for (int i = base + t; i < end; i += 256) {
    unsigned int v = binned[i];
    int d = (int)(v & 0xFFFFu) - lo;
    int p = atomicAdd(&cnt[d], 1);
    int s = (int)(v >> 16);
    if (p < STAGE_MAX) staging[p] = s;
    else csr_src[base + p] = s;
  }
  __syncthreads();
  int tot = end - base;
  int lim = tot < STAGE_MAX ? tot : STAGE_MAX;
  for (int k = t; k < lim; k += 256) csr_src[base + k] = staging[k];
}

// ---------------- layer 0 GEMM via f16 MFMA: h0 = xh @ W0 + fused att dots ----------------
// wave handles 16 rows x 128 cols; A row = lane&15, k-group = lane>>4 (8 contig k);
// D: col = lane&15, row = (lane>>4)*4 + reg  [verified mapping]
__global__ __launch_bounds__(256) void k_gemm0m(
    const _Float16* __restrict__ xh, const _Float16* __restrict__ Wt,
    const float* __restrict__ att_s, const float* __restrict__ att_d,
    _Float16* __restrict__ h, float* __restrict__ a_src, float* __restrict__ a_dst) {
  int lane = threadIdx.x & 63;
  int wv = threadIdx.x >> 6;
  int row0 = blockIdx.x * 64 + wv * 16;
  int m = lane & 15, kg = lane >> 4;
  int arow = row0 + m;
  int arowc = arow < N_NODES ? arow : N_NODES - 1;
  f32x4 acc[8];
#pragma unroll
  for (int ct = 0; ct < 8; ct++) acc[ct] = (f32x4){0.f, 0.f, 0.f, 0.f};
#pragma unroll
  for (int kc = 0; kc < 4; kc++) {
    half8 af = *(const half8*)&xh[(size_t)arowc * 128 + kc * 32 + kg * 8];
#pragma unroll
    for (int ct = 0; ct < 8; ct++) {
      half8 bf = *(const half8*)&Wt[(ct * 16 + m) * 128 + kc * 32 + kg * 8];
      acc[ct] = __builtin_amdgcn_mfma_f32_16x16x32_f16(af, bf, acc[ct], 0, 0, 0);
    }
  }
  float as[8], ad[8];
#pragma unroll
  for (int ct = 0; ct < 8; ct++) { as[ct] = att_s[ct * 16 + m]; ad[ct] = att_d[ct * 16 + m]; }
#pragma unroll
  for (int r = 0; r < 4; r++) {
    int row = row0 + kg * 4 + r;
    bool ok = row < N_NODES;
    float ps0 = 0.f, pd0 = 0.f, ps1 = 0.f, pd1 = 0.f;
#pragma unroll
    for (int ct = 0; ct < 4; ct++) { ps0 += acc[ct][r] * as[ct]; pd0 += acc[ct][r] * ad[ct]; }
#pragma unroll
    for (int ct = 4; ct < 8; ct++) { ps1 += acc[ct][r] * as[ct]; pd1 += acc[ct][r] * ad[ct]; }
#pragma unroll
    for (int msk = 1; msk <= 8; msk <<= 1) {
      ps0 += __shfl_xor(ps0, msk); pd0 += __shfl_xor(pd0, msk);
      ps1 += __shfl_xor(ps1, msk); pd1 += __shfl_xor(pd1, msk);
    }
    if (ok) {
#pragma unroll
      for (int ct = 0; ct < 8; ct++)
        h[(size_t)row * 128 + ct * 16 + m] = (_Float16)acc[ct][r];
      if (m == 0) {
        a_src[row * 2 + 0] = ps0; a_dst[row * 2 + 0] = pd0;
        a_src[row * 2 + 1] = ps1; a_dst[row * 2 + 1] = pd1;
      }
    }
  }
}

// ---------------- layer 1 GEMM via f16 MFMA: h1 = yh @ W1 + fused att dots ----------------
__global__ __launch_bounds__(256) void k_gemm1m(
    const _Float16* __restrict__ yh, const _Float16* __restrict__ Wt,
    const float* __restrict__ att_s, const float* __restrict__ att_d,
    _Float16* __restrict__ h, float* __restrict__ a_src, float* __restrict__ a_dst) {
  int lane = threadIdx.x & 63;
  int wv = threadIdx.x >> 6;
  int row0 = blockIdx.x * 64 + wv * 16;
  int m = lane & 15, kg = lane >> 4;
  int arow = row0 + m;
  int arowc = arow < N_NODES ? arow : N_NODES - 1;
  f32x4 acc[4];
#pragma unroll
  for (int ct = 0; ct < 4; ct++) acc[ct] = (f32x4){0.f, 0.f, 0.f, 0.f};
#pragma unroll
  for (int kc = 0; kc < 4; kc++) {
    half8 af = *(const half8*)&yh[(size_t)arowc * 128 + kc * 32 + kg * 8];
#pragma unroll
    for (int ct = 0; ct < 4; ct++) {
      half8 bf = *(const half8*)&Wt[(ct * 16 + m) * 128 + kc * 32 + kg * 8];
      acc[ct] = __builtin_amdgcn_mfma_f32_16x16x32_f16(af, bf, acc[ct], 0, 0, 0);
    }
  }
  float as[4], ad[4];
#pragma unroll
  for (int ct = 0; ct < 4; ct++) { as[ct] = att_s[ct * 16 + m]; ad[ct] = att_d[ct * 16 + m]; }
#pragma unroll
  for (int r = 0; r < 4; r++) {
    int row = row0 + kg * 4 + r;
    bool ok = row < N_NODES;
    float ps = 0.f, pd = 0.f;
#pragma unroll
    for (int ct = 0; ct < 4; ct++) { ps += acc[ct][r] * as[ct]; pd += acc[ct][r] * ad[ct]; }
#pragma unroll
    for (int msk = 1; msk <= 8; msk <<= 1) {
      ps += __shfl_xor(ps, msk); pd += __shfl_xor(pd, msk);
    }
    if (ok) {
#pragma unroll
      for (int ct = 0; ct < 4; ct++)
        h[(size_t)row * 64 + ct * 16 + m] = (_Float16)acc[ct][r];
      if (m == 0) { a_src[row] = ps; a_dst[row] = pd; }
    }
  }
}

// ---------------- layer 0 aggregation (unchanged) ----------------
__global__ __launch_bounds__(256) void k_agg0(
    const int* __restrict__ row_ptr, const int* __restrict__ csr_src,
    const __half* __restrict__ h, const float* __restrict__ a_src,
    const float* __restrict__ a_dst, const float* __restrict__ bias,
    float* __restrict__ out) {
  int node = (blockIdx.x * blockDim.x + threadIdx.x) >> 6;
  if (node >= N_NODES) return;
  int l = threadIdx.x & 63;
  int head = l >> 5;
  int c = l * 2;
  float ad = a_dst[node * 2 + head];
  float m = lrelu(a_src[node * 2 + head] + ad);
  float d = 1.f;
  float2 hv = __half22float2(*(const __half2*)&h[(size_t)node * 128 + c]);
  float acc0 = hv.x, acc1 = hv.y;
  int beg = row_ptr[node], end = row_ptr[node + 1];
  int i = beg;
  for (; i + 8 <= end; i += 8) {
    int s0 = csr_src[i], s1 = csr_src[i + 1], s2 = csr_src[i + 2], s3 = csr_src[i + 3];
    int s4 = csr_src[i + 4], s5 = csr_src[i + 5], s6 = csr_src[i + 6], s7 = csr_src[i + 7];
    float e0 = lrelu(a_src[s0 * 2 + head] + ad), e1 = lrelu(a_src[s1 * 2 + head] + ad);
    float e2 = lrelu(a_src[s2 * 2 + head] + ad), e3 = lrelu(a_src[s3 * 2 + head] + ad);
    float e4 = lrelu(a_src[s4 * 2 + head] + ad), e5 = lrelu(a_src[s5 * 2 + head] + ad);
    float e6 = lrelu(a_src[s6 * 2 + head] + ad), e7 = lrelu(a_src[s7 * 2 + head] + ad);
    __half2 p0 = *(const __half2*)&h[(size_t)s0 * 128 + c];
    __half2 p1 = *(const __half2*)&h[(size_t)s1 * 128 + c];
    __half2 p2 = *(const __half2*)&h[(size_t)s2 * 128 + c];
    __half2 p3 = *(const __half2*)&h[(size_t)s3 * 128 + c];
    __half2 p4 = *(const __half2*)&h[(size_t)s4 * 128 + c];
    __half2 p5 = *(const __half2*)&h[(size_t)s5 * 128 + c];
    __half2 p6 = *(const __half2*)&h[(size_t)s6 * 128 + c];
    __half2 p7 = *(const __half2*)&h[(size_t)s7 * 128 + c];
    float nm = fmaxf(m, fmaxf(fmaxf(fmaxf(e0, e1), fmaxf(e2, e3)),
                              fmaxf(fmaxf(e4, e5), fmaxf(e6, e7))));
    float sc = __expf(m - nm);
    float w0 = __expf(e0 - nm), w1 = __expf(e1 - nm), w2 = __expf(e2 - nm), w3 = __expf(e3 - nm);
    float w4 = __expf(e4 - nm), w5 = __expf(e5 - nm), w6 = __expf(e6 - nm), w7 = __expf(e7 - nm);
    d = d * sc + ((w0 + w1) + (w2 + w3)) + ((w4 + w5) + (w6 + w7));
    float2 f0 = __half22float2(p0), f1 = __half22float2(p1);
    float2 f2 = __half22float2(p2), f3 = __half22float2(p3);
    float2 f4 = __half22float2(p4), f5 = __half22float2(p5);
    float2 f6 = __half22float2(p6), f7 = __half22float2(p7);
    acc0 = acc0 * sc + (w0 * f0.x + w1 * f1.x + w2 * f2.x + w3 * f3.x) +
           (w4 * f4.x + w5 * f5.x + w6 * f6.x + w7 * f7.x);
    acc1 = acc1 * sc + (w0 * f0.y + w1 * f1.y + w2 * f2.y + w3 * f3.y) +
           (w4 * f4.y + w5 * f5.y + w6 * f6.y + w7 * f7.y);
    m = nm;
  }
  for (; i + 4 <= end; i += 4) {
    int s0 = csr_src[i], s1 = csr_src[i + 1], s2 = csr_src[i + 2], s3 = csr_src[i + 3];
    float e0 = lrelu(a_src[s0 * 2 + head] + ad), e1 = lrelu(a_src[s1 * 2 + head] + ad);
    float e2 = lrelu(a_src[s2 * 2 + head] + ad), e3 = lrelu(a_src[s3 * 2 + head] + ad);
    __half2 p0 = *(const __half2*)&h[(size_t)s0 * 128 + c];
    __half2 p1 = *(const __half2*)&h[(size_t)s1 * 128 + c];
    __half2 p2 = *(const __half2*)&h[(size_t)s2 * 128 + c];
    __half2 p3 = *(const __half2*)&h[(size_t)s3 * 128 + c];
    float nm = fmaxf(fmaxf(m, e0), fmaxf(fmaxf(e1, e2), e3));
    float sc = __expf(m - nm);
    float w0 = __expf(e0 - nm), w1 = __expf(e1 - nm), w2 = __expf(e2 - nm), w3 = __expf(e3 - nm);
    d = d * sc + (w0 + w1) + (w2 + w3);
    float2 f0 = __half22float2(p0), f1 = __half22float2(p1);
    float2 f2 = __half22float2(p2), f3 = __half22float2(p3);
    acc0 = acc0 * sc + w0 * f0.x + w1 * f1.x + w2 * f2.x + w3 * f3.x;
    acc1 = acc1 * sc + w0 * f0.y + w1 * f1.y + w2 * f2.y + w3 * f3.y;
    m = nm;
  }
  for (; i < end; i++) {
    int s = csr_src[i];
    float ee = lrelu(a_src[s * 2 + head] + ad);
    __half2 pp = *(const __half2*)&h[(size_t)s * 128 + c];
    float nm = fmaxf(m, ee);
    float sc = __expf(m - nm);
    float w = __expf(ee - nm);
    float2 ff = __half22float2(pp);
    d = d * sc + w;
    acc0 = acc0 * sc + w * ff.x;
    acc1 = acc1 * sc + w * ff.y;
    m = nm;
  }
  float inv = 1.f / d;
  float2 o;
  o.x = acc0 * inv + bias[c];
  o.y = acc1 * inv + bias[c + 1];
  *(float2*)&out[(size_t)node * 128 + c] = o;
}

// ---------------- BatchNorm stats ----------------
__global__ __launch_bounds__(256) void k_bnstats(const float* __restrict__ x,
                                                 float* __restrict__ bn_sum,
                                                 float* __restrict__ bn_sumsq) {
  int f = threadIdx.x & 127;
  int half = threadIdx.x >> 7;
  float s = 0.f, s2 = 0.f;
  for (int r = blockIdx.x * 2 + half; r < N_NODES; r += gridDim.x * 2) {
    float v = x[(size_t)r * 128 + f];
    s += v;
    s2 += v * v;
  }
  __shared__ float ls[256], ls2[256];
  ls[threadIdx.x] = s;
  ls2[threadIdx.x] = s2;
  __syncthreads();
  if (half == 0) {
    atomicAdd(&bn_sum[f], s + ls[f + 128]);
    atomicAdd(&bn_sumsq[f], s2 + ls2[f + 128]);
  }
}

__global__ void k_bnfinal(const float* __restrict__ sum, const float* __restrict__ sumsq,
                          const float* __restrict__ gamma, const float* __restrict__ beta,
                          float* __restrict__ scale, float* __restrict__ shift) {
  int f = threadIdx.x;
  float mu = sum[f] / (float)N_NODES;
  float var = sumsq[f] / (float)N_NODES - mu * mu;
  float sc = gamma[f] * rsqrtf(var + BN_EPS);
  scale[f] = sc;
  shift[f] = beta[f] - mu * sc;
}

// ---------------- layer 1 aggregation (unchanged) ----------------
__global__ __launch_bounds__(256) void k_agg1(
    const int* __restrict__ row_ptr, const int* __restrict__ csr_src,
    const __half* __restrict__ h, const float* __restrict__ a_src,
    const float* __restrict__ a_dst, const float* __restrict__ bias,
    float* __restrict__ out) {
  int node = (blockIdx.x * blockDim.x + threadIdx.x) >> 6;
  if (node >= N_NODES) return;
  int l = threadIdx.x & 63;
  float ad = a_dst[node];
  float m = lrelu(a_src[node] + ad);
  float d = 1.f;
  float acc = __half2float(h[(size_t)node * 64 + l]);
  int beg = row_ptr[node], end = row_ptr[node + 1];
  int i = beg;
  for (; i + 8 <= end; i += 8) {
    int s0 = csr_src[i], s1 = csr_src[i + 1], s2 = csr_src[i + 2], s3 = csr_src[i + 3];
    int s4 = csr_src[i + 4], s5 = csr_src[i + 5], s6 = csr_src[i + 6], s7 = csr_src[i + 7];
    float e0 = lrelu(a_src[s0] + ad), e1 = lrelu(a_src[s1] + ad);
    float e2 = lrelu(a_src[s2] + ad), e3 = lrelu(a_src[s3] + ad);
    float e4 = lrelu(a_src[s4] + ad), e5 = lrelu(a_src[s5] + ad);
    float e6 = lrelu(a_src[s6] + ad), e7 = lrelu(a_src[s7] + ad);
    __half p0 = h[(size_t)s0 * 64 + l], p1 = h[(size_t)s1 * 64 + l];
    __half p2 = h[(size_t)s2 * 64 + l], p3 = h[(size_t)s3 * 64 + l];
    __half p4 = h[(size_t)s4 * 64 + l], p5 = h[(size_t)s5 * 64 + l];
    __half p6 = h[(size_t)s6 * 64 + l], p7 = h[(size_t)s7 * 64 + l];
    float nm = fmaxf(m, fmaxf(fmaxf(fmaxf(e0, e1), fmaxf(e2, e3)),
                              fmaxf(fmaxf(e4, e5), fmaxf(e6, e7))));
    float sc = __expf(m - nm);
    float w0 = __expf(e0 - nm), w1 = __expf(e1 - nm), w2 = __expf(e2 - nm), w3 = __expf(e3 - nm);
    float w4 = __expf(e4 - nm), w5 = __expf(e5 - nm), w6 = __expf(e6 - nm), w7 = __expf(e7 - nm);
    d = d * sc + ((w0 + w1) + (w2 + w3)) + ((w4 + w5) + (w6 + w7));
    acc = acc * sc +
          (w0 * __half2float(p0) + w1 * __half2float(p1) + w2 * __half2float(p2) +
           w3 * __half2float(p3)) +
          (w4 * __half2float(p4) + w5 * __half2float(p5) + w6 * __half2float(p6) +
           w7 * __half2float(p7));
    m = nm;
  }
  for (; i + 4 <= end; i += 4) {
    int s0 = csr_src[i], s1 = csr_src[i + 1], s2 = csr_src[i + 2], s3 = csr_src[i + 3];
    float e0 = lrelu(a_src[s0] + ad), e1 = lrelu(a_src[s1] + ad);
    float e2 = lrelu(a_src[s2] + ad), e3 = lrelu(a_src[s3] + ad);
    __half p0 = h[(size_t)s0 * 64 + l], p1 = h[(size_t)s1 * 64 + l];
    __half p2 = h[(size_t)s2 * 64 + l], p3 = h[(size_t)s3 * 64 + l];
    float nm = fmaxf(fmaxf(m, e0), fmaxf(fmaxf(e1, e2), e3));
    float sc = __expf(m - nm);
    float w0 = __expf(e0 - nm), w1 = __expf(e1 - nm), w2 = __expf(e2 - nm), w3 = __expf(e3 - nm);
    d = d * sc + (w0 + w1) + (w2 + w3);
    acc = acc * sc + w0 * __half2float(p0) + w1 * __half2float(p1) + w2 * __half2float(p2) +
          w3 * __half2float(p3);
    m = nm;
  }
  for (; i < end; i++) {
    int s = csr_src[i];
    float ee = lrelu(a_src[s] + ad);
    __half pp = h[(size_t)s * 64 + l];
    float nm = fmaxf(m, ee);
    float sc = __expf(m - nm);
    float w = __expf(ee - nm);
    d = d * sc + w;
    acc = acc * sc + w * __half2float(pp);
    m = nm;
  }
  out[(size_t)node * 64 + l] = acc / d + bias[l];
}

// ---------------- launch ----------------
extern "C" void kernel_launch(void* const* d_in, const int* in_sizes, int n_in,
                              void* d_out, int out_size, void* d_ws, size_t ws_size,
                              hipStream_t stream) {
  const float* data = (const float*)d_in[0];
  const int* ei = (const int*)d_in[1];
  const float* W0 = (const float*)d_in[2];
  const float* att_src0 = (const float*)d_in[3];
  const float* att_dst0 = (const float*)d_in[4];
  const float* bias0 = (const float*)d_in[5];
  const float* gamma0 = (const float*)d_in[6];
  const float* beta0 = (const float*)d_in[7];
  const float* W1 = (const float*)d_in[8];
  const float* att_src1 = (const float*)d_in[9];
  const float* att_dst1 = (const float*)d_in[10];
  const float* bias1 = (const float*)d_in[11];
  float* out = (float*)d_out;

  char* ws = (char*)d_ws;
  size_t off = 0;
  auto alloc = [&](size_t bytes) -> void* {
    void* p = ws + off;
    off = (off + bytes + 255) & ~(size_t)255;
    return p;
  };
  int* cnt = (int*)alloc((size_t)CNT_N * 4);
  int* tmp = (int*)alloc((size_t)CNT_N * 4);
  int* bsums = (int*)alloc(32 * 4);
  int* bucket_base = (int*)alloc((NBK + 1) * 4);
  int* row_ptr = (int*)alloc((N_NODES + 1) * 4);
  unsigned int* binned = (unsigned int*)alloc((size_t)E_EDGES * 4);
  int* csr_src = (int*)alloc((size_t)E_EDGES * 4);
  _Float16* xh = (_Float16*)alloc((size_t)N_NODES * 128 * 2);
  _Float16* W0t = (_Float16*)alloc(128 * 128 * 2);
  _Float16* W1t = (_Float16*)alloc(64 * 128 * 2);
  _Float16* h0 = (_Float16*)alloc((size_t)N_NODES * 128 * 2);
  float* a_s0 = (float*)alloc((size_t)N_NODES * 2 * 4);
  float* a_d0 = (float*)alloc((size_t)N_NODES * 2 * 4);
  float* out0 = (float*)alloc((size_t)N_NODES * 128 * 4);
  _Float16* yh = (_Float16*)alloc((size_t)N_NODES * 128 * 2);
  float* bn_sum = (float*)alloc(128 * 4);
  float* bn_sumsq = (float*)alloc(128 * 4);
  float* bn_scale = (float*)alloc(128 * 4);
  float* bn_shift = (float*)alloc(128 * 4);
  _Float16* h1 = h0;  // alias: h0 dead after agg0
  float* a_s1 = a_s0;
  float* a_d1 = a_d0;

  const int* srcArr = ei;
  const int* dstArr = ei + E_EDGES;

  k_zero<<<1, 128, 0, stream>>>(bn_sum, bn_sumsq);
  k_cvtW<<<1, 256, 0, stream>>>(W0, W1, W0t, W1t);
  k_cvtx<<<3125, 256, 0, stream>>>(data, xh);
  k_l1hist<<<L1_BLOCKS, 256, 0, stream>>>(dstArr, cnt);
  k_scan1g<<<SCG_BLOCKS, 256, 0, stream>>>(cnt, tmp, bsums);
  k_scan2g<<<1, 64, 0, stream>>>(bsums);
  k_l1scatter<<<L1_BLOCKS, 256, 0, stream>>>(srcArr, dstArr, tmp, bsums, binned);
  k_bbase<<<1, 128, 0, stream>>>(tmp, bsums, bucket_base);
  k_scatter3<<<NBK, 256, 0, stream>>>(bucket_base, binned, row_ptr, csr_src);
  k_gemm0m<<<(N_NODES + 63) / 64, 256, 0, stream>>>(xh, W0t, att_src0, att_dst0, h0, a_s0, a_d0);
  k_agg0<<<(N_NODES + 3) / 4, 256, 0, stream>>>(row_ptr, csr_src, (const __half*)h0, a_s0, a_d0,
                                                bias0, out0);
  k_bnstats<<<1024, 256, 0, stream>>>(out0, bn_sum, bn_sumsq);
  k_bnfinal<<<1, 128, 0, stream>>>(bn_sum, bn_sumsq, gamma0, beta0, bn_scale, bn_shift);
  k_cvty<<<3125, 256, 0, stream>>>(out0, bn_scale, bn_shift, yh);
  k_gemm1m<<<(N_NODES + 63) / 64, 256, 0, stream>>>(yh, W1t, att_src1, att_dst1, h1, a_s1, a_d1);
  k_agg1<<<(N_NODES + 3) / 4, 256, 0, stream>>>(row_ptr, csr_src, (const __half*)h1, a_s1, a_d1,
                                                bias1, out);
}